// Round 5
// baseline (209.173 us; speedup 1.0000x reference)
//
#include <hip/hip_runtime.h>
#include <stdint.h>
#include <stddef.h>

// Problem dims (fixed by reference)
#define BB 8192
#define TT 26
#define VV 23
#define EE 100
#define HH 128
#define LL 64

typedef __attribute__((ext_vector_type(8))) short bf16x8;  // 8 bf16 = 4 VGPRs
typedef __attribute__((ext_vector_type(4))) float f32x4;   // MFMA 16x16 C/D

#define MFMA(a, b, c) __builtin_amdgcn_mfma_f32_16x16x32_bf16((a), (b), (c), 0, 0, 0)

// ---------------- workspace layout (bytes) ----------------
#define OFF_GRUW   0ull                  // GRU Whh B-frags: 24ct*4kc*1024
#define OFF_TBL    98304ull              // one-hot table B-frags: 24ct*1024
#define OFF_LSTMW  122880ull             // LSTM fused W B-frags: 28ct*8kc*1024 (kc0-3=y, kc4-7=h)
#define OFF_OUTW   352256ull             // out_w B-frags: 2ct*4kc*1024
#define OFF_FCZW   360448ull             // fc_z_w B-frags: 8ct*2kc*1024
#define OFF_LBIAS  376832ull             // fused LSTM bias 4*112 fp32
#define OFF_Y      379904ull             // y/h A-frags (in-place reuse): 512 btile * 26 t * 4 kc * 1024B

// Pin a loaded fragment in VGPRs: opaque asm stops LICM from re-sinking the
// load into the scan loop (R4: VGPR_Count=56 proved weights were re-streamed
// from L2 every phase because ws-aliasing blocked register caching).
__device__ __forceinline__ void force_frag(bf16x8& v) { asm volatile("" : "+v"(v)); }

// Exact RNE (prep only)
__device__ __forceinline__ unsigned short f2bf(float f) {
  union { float f; unsigned u; } v; v.f = f;
  unsigned u = v.u;
  return (unsigned short)((u + 0x7FFFu + ((u >> 16) & 1u)) >> 16);
}
// Fast in-loop convert (round-half-up)
__device__ __forceinline__ unsigned short f2bf_fast(float f) {
  union { float f; unsigned u; } v; v.f = f;
  return (unsigned short)((v.u + 0x8000u) >> 16);
}
#define LOG2E 1.4426950408889634f
__device__ __forceinline__ float sigm(float x) {
  return __builtin_amdgcn_rcpf(1.0f + __builtin_amdgcn_exp2f(-x * LOG2E));
}
__device__ __forceinline__ float tanh_(float x) {
  return __builtin_fmaf(-2.0f,
      __builtin_amdgcn_rcpf(1.0f + __builtin_amdgcn_exp2f(x * (2.0f * LOG2E))), 1.0f);
}

// =====================================================================
// K0: weight swizzle into MFMA B-frag order. Frag (ct,kc): lane holds
// B[k][n], n = ct*16+(lane&15), k = kc*32 + ((lane>>4)&3)*8 + j.
// =====================================================================
__global__ __launch_bounds__(256) void prep_kernel(
    const float* __restrict__ emb, const float* __restrict__ fc_z_w,
    const float* __restrict__ gru_wih, const float* __restrict__ gru_whh,
    const float* __restrict__ gru_bih,
    const float* __restrict__ lstm_wih, const float* __restrict__ lstm_whh,
    const float* __restrict__ lstm_bih, const float* __restrict__ lstm_bhh,
    const float* __restrict__ out_w,
    char* __restrict__ ws)
{
  int e = blockIdx.x * 256 + threadIdx.x;

  if (e < 49152) {  // GRU Whh (384x128)
    int j = e & 7, lane = (e >> 3) & 63, kc = (e >> 9) & 3, ct = e >> 11;
    int n = ct * 16 + (lane & 15);
    int k = kc * 32 + ((lane >> 4) & 3) * 8 + j;
    *(unsigned short*)(ws + OFF_GRUW + (size_t)e * 2) = f2bf(gru_whh[n * HH + k]);
    return;
  }
  e -= 49152;
  if (e < 12288) {  // one-hot table: emb[k]@gru_wih[n] + bih[n]
    int j = e & 7, lane = (e >> 3) & 63, ct = e >> 9;
    int n = ct * 16 + (lane & 15);
    int k = ((lane >> 4) & 3) * 8 + j;
    float v = 0.0f;
    if (k < VV) {
      float s0 = 0.f, s1 = 0.f, s2 = 0.f, s3 = 0.f;
      const float* ep = emb + k * EE;
      const float* wp = gru_wih + n * EE;
#pragma unroll 5
      for (int m = 0; m < EE; m += 4) {
        s0 += ep[m] * wp[m];     s1 += ep[m + 1] * wp[m + 1];
        s2 += ep[m + 2] * wp[m + 2]; s3 += ep[m + 3] * wp[m + 3];
      }
      v = gru_bih[n] + ((s0 + s1) + (s2 + s3));
    }
    *(unsigned short*)(ws + OFF_TBL + (size_t)e * 2) = f2bf(v);
    return;
  }
  e -= 12288;
  if (e < 114688) {  // LSTM fused W: row=112g+c, K=[y 0..127 | h 0..127]
    int j = e & 7, lane = (e >> 3) & 63, kc = (e >> 9) & 7, ct = e >> 12;
    int row = ct * 16 + (lane & 15);
    int g = row / 112, c = row % 112;
    int q = (lane >> 4) & 3;
    float v = 0.0f;
    if (c < EE) {
      if (kc < 4) {
        int k = kc * 32 + q * 8 + j;
        v = lstm_wih[(g * EE + c) * HH + k];
      } else {
        int k = (kc - 4) * 32 + q * 8 + j;
        if (k < EE) v = lstm_whh[(g * EE + c) * EE + k];
      }
    }
    *(unsigned short*)(ws + OFF_LSTMW + (size_t)e * 2) = f2bf(v);
    return;
  }
  e -= 114688;
  if (e < 4096) {  // out_w (23x100 -> 32x128)
    int j = e & 7, lane = (e >> 3) & 63, kc = (e >> 9) & 3, ct = e >> 11;
    int n = ct * 16 + (lane & 15);
    int k = kc * 32 + ((lane >> 4) & 3) * 8 + j;
    float v = (n < VV && k < EE) ? out_w[n * EE + k] : 0.0f;
    *(unsigned short*)(ws + OFF_OUTW + (size_t)e * 2) = f2bf(v);
    return;
  }
  e -= 4096;
  if (e < 8192) {  // fc_z_w (128x64)
    int j = e & 7, lane = (e >> 3) & 63, kc = (e >> 9) & 1, ct = e >> 10;
    int n = ct * 16 + (lane & 15);
    int k = kc * 32 + ((lane >> 4) & 3) * 8 + j;
    *(unsigned short*)(ws + OFF_FCZW + (size_t)e * 2) = f2bf(fc_z_w[n * LL + k]);
    return;
  }
  e -= 8192;
  if (e < 448) {  // fused LSTM bias
    int g = e / 112, c = e % 112;
    float v = (c < EE) ? (lstm_bih[g * EE + c] + lstm_bhh[g * EE + c]) : 0.0f;
    *(float*)(ws + OFF_LBIAS + (size_t)e * 4) = v;
  }
}

// =====================================================================
// K1: GRU scan. 512 blocks x 512 thr (8 waves), 16 rows/block.
// Weights in forced VGPRs (alias-separated restrict pointers).
// y-export issued at the START of the next phase (off the barrier drain).
// =====================================================================
__global__ __launch_bounds__(512, 4) void gru_kernel(
    const float* __restrict__ z, const int* __restrict__ x_in,
    const float* __restrict__ fc_z_b, const float* __restrict__ gru_bhh,
    const unsigned short* __restrict__ gruw, const unsigned short* __restrict__ tbl,
    const unsigned short* __restrict__ fczw, unsigned short* __restrict__ yout)
{
  __shared__ unsigned short hfrag[2][2048];   // 4 kc frags of 1024B each
  __shared__ unsigned char idx_lds[TT * 16];
  const int tid  = threadIdx.x;
  const int wv   = tid >> 6;
  const int lane = tid & 63;
  const int l15  = lane & 15;
  const int q    = (lane >> 4) & 3;
  const int blk  = blockIdx.x;

  for (int i = tid; i < TT * 16; i += 512) {
    int t = i >> 4, r = i & 15;
    idx_lds[i] = (unsigned char)x_in[(blk * 16 + r) * TT + t];
  }

  // stationary weight fragments — loaded once, pinned in VGPRs
  bf16x8 gw[3][4], tw[3];
#pragma unroll
  for (int g = 0; g < 3; g++) {
    int ct = g * 8 + wv;
#pragma unroll
    for (int kc = 0; kc < 4; kc++) {
      gw[g][kc] = *(const bf16x8*)(gruw + (size_t)(ct * 4 + kc) * 512 + lane * 8);
      force_frag(gw[g][kc]);
    }
    tw[g] = *(const bf16x8*)(tbl + (size_t)ct * 512 + lane * 8);
    force_frag(tw[g]);
  }
  const int col = wv * 16 + l15;
  const float b_r = gru_bhh[0 * HH + col];
  const float b_z = gru_bhh[1 * HH + col];
  const float b_n = gru_bhh[2 * HH + col];
  const int wbase = (col >> 5) * 512 + ((col >> 3) & 3) * 128 + (col & 7);

  // h0 = tanh(z @ fc_z_w^T + fc_z_b) via MFMA
  float h[4];
  {
    bf16x8 fw0 = *(const bf16x8*)(fczw + (size_t)(wv * 2 + 0) * 512 + lane * 8);
    bf16x8 fw1 = *(const bf16x8*)(fczw + (size_t)(wv * 2 + 1) * 512 + lane * 8);
    const float* zp = z + (size_t)(blk * 16 + l15) * LL + q * 8;
    f32x4 z0 = *(const f32x4*)(zp);
    f32x4 z1 = *(const f32x4*)(zp + 4);
    f32x4 z2 = *(const f32x4*)(zp + 32);
    f32x4 z3 = *(const f32x4*)(zp + 36);
    bf16x8 za0, za1;
#pragma unroll
    for (int j = 0; j < 4; j++) {
      za0[j]     = (short)f2bf(z0[j]);
      za0[4 + j] = (short)f2bf(z1[j]);
      za1[j]     = (short)f2bf(z2[j]);
      za1[4 + j] = (short)f2bf(z3[j]);
    }
    float fzb = fc_z_b[col];
    f32x4 acc = {fzb, fzb, fzb, fzb};
    acc = MFMA(za0, fw0, acc);
    acc = MFMA(za1, fw1, acc);
#pragma unroll
    for (int i = 0; i < 4; i++) {
      h[i] = tanh_(acc[i]);
      hfrag[0][wbase + (q * 4 + i) * 8] = f2bf_fast(h[i]);
    }
  }
  __syncthreads();

  int cur = 0;
  for (int t = 0; t < TT; t++) {
    // export y(t-1) EARLY (stores get a full phase before the next vmcnt(0))
    if (t > 0 && wv < 4) {
      bf16x8 yv = *(const bf16x8*)((const char*)hfrag[cur] + wv * 1024 + lane * 16);
      *(bf16x8*)(yout + ((size_t)(blk * TT + (t - 1)) * 4 + wv) * 512 + lane * 8) = yv;
    }
    // h-independent part: bias init + one-hot table MFMAs
    int iv = idx_lds[t * 16 + l15];
    bf16x8 oh;
#pragma unroll
    for (int j = 0; j < 8; j++)
      oh[j] = (short)((iv == q * 8 + j) ? 0x3F80 : 0);

    f32x4 ar  = {b_r, b_r, b_r, b_r};
    f32x4 az  = {b_z, b_z, b_z, b_z};
    f32x4 ahn = {b_n, b_n, b_n, b_n};
    f32x4 axn = {0.0f, 0.0f, 0.0f, 0.0f};
    ar  = MFMA(oh, tw[0], ar);
    az  = MFMA(oh, tw[1], az);
    axn = MFMA(oh, tw[2], axn);

    // h-dependent part: conflict-free b128 A-frag reads
    bf16x8 a[4];
#pragma unroll
    for (int kc = 0; kc < 4; kc++)
      a[kc] = *(const bf16x8*)((const char*)hfrag[cur] + kc * 1024 + lane * 16);
#pragma unroll
    for (int kc = 0; kc < 4; kc++) {
      ar  = MFMA(a[kc], gw[0][kc], ar);
      az  = MFMA(a[kc], gw[1][kc], az);
      ahn = MFMA(a[kc], gw[2][kc], ahn);
    }

    int nb = cur ^ 1;
#pragma unroll
    for (int i = 0; i < 4; i++) {
      float r  = sigm(ar[i]);
      float zg = sigm(az[i]);
      float n  = tanh_(__builtin_fmaf(r, ahn[i], axn[i]));
      h[i] = __builtin_fmaf(zg, h[i] - n, n);
      hfrag[nb][wbase + (q * 4 + i) * 8] = f2bf_fast(h[i]);
    }
    __syncthreads();
    cur = nb;
  }
  // tail: export y(TT-1)
  if (wv < 4) {
    bf16x8 yv = *(const bf16x8*)((const char*)hfrag[cur] + wv * 1024 + lane * 16);
    *(bf16x8*)(yout + ((size_t)(blk * TT + (TT - 1)) * 4 + wv) * 512 + lane * 8) = yv;
  }
}

// =====================================================================
// K2: LSTM scan, wave-specialized, no logits. 512 blocks x 896 thr
// (14 waves), 16 rows/block. Waves 0-6: y-projection -> P (LDS), plus
// h-export (2-phase lag, in-place into the y slot). Waves 7-13: recurrent.
// Weights pinned in VGPRs via restrict pointers + force_frag.
// =====================================================================
__global__ __launch_bounds__(896, 4) void lstm_kernel(
    const unsigned short* __restrict__ lstmw, const float* __restrict__ lbias,
    unsigned short* __restrict__ ybuf)
{
  __shared__ float Pbuf[2][4 * 7 * 64 * 4];       // 28 KB per buffer
  __shared__ unsigned short hbuf[2][2048];        // 4 KB per buffer (A-frags)
  const int tid  = threadIdx.x;
  const int wv   = tid >> 6;        // 0..13
  const int lane = tid & 63;
  const int l15  = lane & 15;
  const int q    = (lane >> 4) & 3;
  const int blk  = blockIdx.x;      // 0..511

  for (int i = tid; i < 4096; i += 896)
    ((unsigned short*)hbuf)[i] = 0;
  __syncthreads();

  if (wv < 7) {
    // ---------------- y-projection + h-export waves ----------------
    bf16x8 lwy[4][4];
#pragma unroll
    for (int g = 0; g < 4; g++)
#pragma unroll
      for (int kc = 0; kc < 4; kc++) {
        lwy[g][kc] = *(const bf16x8*)(lstmw + (size_t)((g * 7 + wv) * 8 + kc) * 512 + lane * 8);
        force_frag(lwy[g][kc]);
      }
    const int col = wv * 16 + l15;
    float b[4];
#pragma unroll
    for (int g = 0; g < 4; g++) b[g] = lbias[g * 112 + col];

    bf16x8 ya[4];
#pragma unroll
    for (int kc = 0; kc < 4; kc++)
      ya[kc] = *(const bf16x8*)(ybuf + ((size_t)(blk * TT + 0) * 4 + kc) * 512 + lane * 8);

    for (int p = 0; p < TT + 2; p++) {
      // export h(p-2) EARLY into its (dead) y slot
      if (p >= 2 && wv < 4) {
        bf16x8 hv = *(const bf16x8*)((const char*)hbuf[p & 1] + wv * 1024 + lane * 16);
        *(bf16x8*)(ybuf + ((size_t)(blk * TT + (p - 2)) * 4 + wv) * 512 + lane * 8) = hv;
      }
      if (p <= TT - 1) {
#pragma unroll
        for (int g = 0; g < 4; g++) {
          f32x4 acc = {b[g], b[g], b[g], b[g]};
#pragma unroll
          for (int kc = 0; kc < 4; kc++)
            acc = MFMA(ya[kc], lwy[g][kc], acc);
          *(f32x4*)&Pbuf[p & 1][((g * 7 + wv) * 64 + lane) * 4] = acc;
        }
        if (p < TT - 1) {
#pragma unroll
          for (int kc = 0; kc < 4; kc++)
            ya[kc] = *(const bf16x8*)(ybuf + ((size_t)(blk * TT + p + 1) * 4 + kc) * 512 + lane * 8);
        }
      }
      __syncthreads();
    }
  } else {
    // ---------------- recurrent waves ----------------
    const int tile = wv - 7;
    bf16x8 lwh[4][4];
#pragma unroll
    for (int g = 0; g < 4; g++)
#pragma unroll
      for (int kc = 0; kc < 4; kc++) {
        lwh[g][kc] = *(const bf16x8*)(lstmw + (size_t)((g * 7 + tile) * 8 + kc + 4) * 512 + lane * 8);
        force_frag(lwh[g][kc]);
      }
    const int col = tile * 16 + l15;
    const int wbase = (col >> 5) * 512 + ((col >> 3) & 3) * 128 + (col & 7);
    float c[4] = {0, 0, 0, 0};

    for (int p = 0; p < TT + 2; p++) {
      if (p >= 1 && p <= TT) {
        const int rb = (p - 1) & 1;
        f32x4 ai = *(const f32x4*)&Pbuf[rb][((0 * 7 + tile) * 64 + lane) * 4];
        f32x4 af = *(const f32x4*)&Pbuf[rb][((1 * 7 + tile) * 64 + lane) * 4];
        f32x4 ag = *(const f32x4*)&Pbuf[rb][((2 * 7 + tile) * 64 + lane) * 4];
        f32x4 ao = *(const f32x4*)&Pbuf[rb][((3 * 7 + tile) * 64 + lane) * 4];
        bf16x8 ha[4];
#pragma unroll
        for (int kc = 0; kc < 4; kc++)
          ha[kc] = *(const bf16x8*)((const char*)hbuf[p & 1] + kc * 1024 + lane * 16);
#pragma unroll
        for (int kc = 0; kc < 4; kc++) {
          ai = MFMA(ha[kc], lwh[0][kc], ai);
          af = MFMA(ha[kc], lwh[1][kc], af);
          ag = MFMA(ha[kc], lwh[2][kc], ag);
          ao = MFMA(ha[kc], lwh[3][kc], ao);
        }
#pragma unroll
        for (int i = 0; i < 4; i++) {
          float ii = sigm(ai[i]), ff = sigm(af[i]);
          float gg = tanh_(ag[i]), oo = sigm(ao[i]);
          float cn = __builtin_fmaf(ff, c[i], ii * gg);
          c[i] = cn;
          hbuf[rb][wbase + (q * 4 + i) * 8] = f2bf_fast(oo * tanh_(cn));
        }
      }
      __syncthreads();
    }
  }
}

// =====================================================================
// K3: logits GEMM, barrier-free. 512 blocks x 512 thr (8 waves).
// Block = btile; wave wv handles t = wv, wv+8, ... Reads h A-frags
// (written in-place by K2), out_w B-frags; scatter-stores 16x23 tiles.
// =====================================================================
__global__ __launch_bounds__(512) void logits_kernel(
    const float* __restrict__ out_b, const unsigned short* __restrict__ hg,
    const unsigned short* __restrict__ outw, float* __restrict__ out)
{
  const int tid  = threadIdx.x;
  const int wv   = tid >> 6;        // 0..7
  const int lane = tid & 63;
  const int l15  = lane & 15;
  const int q    = (lane >> 4) & 3;
  const int blk  = blockIdx.x;      // 0..511

  bf16x8 ow[2][4];
#pragma unroll
  for (int ct = 0; ct < 2; ct++)
#pragma unroll
    for (int kc = 0; kc < 4; kc++) {
      ow[ct][kc] = *(const bf16x8*)(outw + (size_t)(ct * 4 + kc) * 512 + lane * 8);
      force_frag(ow[ct][kc]);
    }
  float ob[2];
#pragma unroll
  for (int ct = 0; ct < 2; ct++) {
    int cv = ct * 16 + l15;
    ob[ct] = (cv < VV) ? out_b[cv] : 0.0f;
  }

  for (int t = wv; t < TT; t += 8) {
    bf16x8 ha[4];
#pragma unroll
    for (int kc = 0; kc < 4; kc++)
      ha[kc] = *(const bf16x8*)(hg + ((size_t)(blk * TT + t) * 4 + kc) * 512 + lane * 8);
#pragma unroll
    for (int ct = 0; ct < 2; ct++) {
      f32x4 acc = {ob[ct], ob[ct], ob[ct], ob[ct]};
#pragma unroll
      for (int kc = 0; kc < 4; kc++)
        acc = MFMA(ha[kc], ow[ct][kc], acc);
      int cv = ct * 16 + l15;
      if (cv < VV) {
#pragma unroll
        for (int i = 0; i < 4; i++) {
          int rowg = blk * 16 + q * 4 + i;
          out[((size_t)rowg * TT + t) * VV + cv] = acc[i];
        }
      }
    }
  }
}

extern "C" void kernel_launch(void* const* d_in, const int* in_sizes, int n_in,
                              void* d_out, int out_size, void* d_ws, size_t ws_size,
                              hipStream_t stream) {
  (void)in_sizes; (void)n_in; (void)out_size; (void)ws_size;
  const float* z        = (const float*)d_in[0];
  const int*   x_in     = (const int*)  d_in[1];
  const float* emb      = (const float*)d_in[2];
  const float* fc_z_w   = (const float*)d_in[3];
  const float* fc_z_b   = (const float*)d_in[4];
  const float* gru_wih  = (const float*)d_in[5];
  const float* gru_whh  = (const float*)d_in[6];
  const float* gru_bih  = (const float*)d_in[7];
  const float* gru_bhh  = (const float*)d_in[8];
  const float* lstm_wih = (const float*)d_in[9];
  const float* lstm_whh = (const float*)d_in[10];
  const float* lstm_bih = (const float*)d_in[11];
  const float* lstm_bhh = (const float*)d_in[12];
  const float* out_w    = (const float*)d_in[13];
  const float* out_b    = (const float*)d_in[14];
  char*  ws  = (char*)d_ws;
  float* out = (float*)d_out;

  const unsigned short* gruw  = (const unsigned short*)(ws + OFF_GRUW);
  const unsigned short* tblp  = (const unsigned short*)(ws + OFF_TBL);
  const unsigned short* lstmw = (const unsigned short*)(ws + OFF_LSTMW);
  const unsigned short* outw  = (const unsigned short*)(ws + OFF_OUTW);
  const unsigned short* fczw  = (const unsigned short*)(ws + OFF_FCZW);
  const float*          lbias = (const float*)(ws + OFF_LBIAS);
  unsigned short*       ybuf  = (unsigned short*)(ws + OFF_Y);

  prep_kernel<<<738, 256, 0, stream>>>(emb, fc_z_w, gru_wih, gru_whh, gru_bih,
                                       lstm_wih, lstm_whh, lstm_bih, lstm_bhh,
                                       out_w, ws);
  gru_kernel<<<512, 512, 0, stream>>>(z, x_in, fc_z_b, gru_bhh,
                                      gruw, tblp, fczw, ybuf);
  lstm_kernel<<<512, 896, 0, stream>>>(lstmw, lbias, ybuf);
  logits_kernel<<<512, 512, 0, stream>>>(out_b, ybuf, outw, out);
}

// Round 6
// 207.884 us; speedup vs baseline: 1.0062x; 1.0062x over previous
//
#include <hip/hip_runtime.h>
#include <stdint.h>
#include <stddef.h>

// Problem dims (fixed by reference)
#define BB 8192
#define TT 26
#define VV 23
#define EE 100
#define HH 128
#define LL 64

typedef __attribute__((ext_vector_type(8))) short bf16x8;  // 8 bf16 = 4 VGPRs
typedef __attribute__((ext_vector_type(4))) float f32x4;   // MFMA 16x16 C/D

#define MFMA(a, b, c) __builtin_amdgcn_mfma_f32_16x16x32_bf16((a), (b), (c), 0, 0, 0)

// ---------------- workspace layout (bytes) ----------------
#define OFF_GRUW   0ull                  // GRU Whh B-frags: 24ct*4kc*1024
#define OFF_TBL    98304ull              // one-hot table B-frags: 24ct*1024
#define OFF_LSTMW  122880ull             // LSTM fused W B-frags: 28ct*8kc*1024 (kc0-3=y, kc4-7=h)
#define OFF_OUTW   352256ull             // out_w B-frags: 2ct*4kc*1024
#define OFF_FCZW   360448ull             // fc_z_w B-frags: 8ct*2kc*1024
#define OFF_LBIAS  376832ull             // fused LSTM bias 4*112 fp32
#define OFF_Y      379904ull             // y A-frags: 512 btile * 26 t * 4 kc * 1024B

// Pin a loaded fragment (stop LICM/RA from re-sinking the load into the
// scan loop). Works only if the launch-bounds register budget has room —
// hence __launch_bounds__(512, 2) (256-reg cap) on the scan kernels.
__device__ __forceinline__ void force_frag(bf16x8& v) { asm volatile("" : "+v"(v)); }

// Exact RNE (prep only)
__device__ __forceinline__ unsigned short f2bf(float f) {
  union { float f; unsigned u; } v; v.f = f;
  unsigned u = v.u;
  return (unsigned short)((u + 0x7FFFu + ((u >> 16) & 1u)) >> 16);
}
// Fast in-loop convert (round-half-up)
__device__ __forceinline__ unsigned short f2bf_fast(float f) {
  union { float f; unsigned u; } v; v.f = f;
  return (unsigned short)((v.u + 0x8000u) >> 16);
}
#define LOG2E 1.4426950408889634f
__device__ __forceinline__ float sigm(float x) {
  return __builtin_amdgcn_rcpf(1.0f + __builtin_amdgcn_exp2f(-x * LOG2E));
}
__device__ __forceinline__ float tanh_(float x) {
  return __builtin_fmaf(-2.0f,
      __builtin_amdgcn_rcpf(1.0f + __builtin_amdgcn_exp2f(x * (2.0f * LOG2E))), 1.0f);
}

// =====================================================================
// K0: weight swizzle into MFMA B-frag order. Frag (ct,kc): lane holds
// B[k][n], n = ct*16+(lane&15), k = kc*32 + ((lane>>4)&3)*8 + j.
// =====================================================================
__global__ __launch_bounds__(256) void prep_kernel(
    const float* __restrict__ emb, const float* __restrict__ fc_z_w,
    const float* __restrict__ gru_wih, const float* __restrict__ gru_whh,
    const float* __restrict__ gru_bih,
    const float* __restrict__ lstm_wih, const float* __restrict__ lstm_whh,
    const float* __restrict__ lstm_bih, const float* __restrict__ lstm_bhh,
    const float* __restrict__ out_w,
    char* __restrict__ ws)
{
  int e = blockIdx.x * 256 + threadIdx.x;

  if (e < 49152) {  // GRU Whh (384x128)
    int j = e & 7, lane = (e >> 3) & 63, kc = (e >> 9) & 3, ct = e >> 11;
    int n = ct * 16 + (lane & 15);
    int k = kc * 32 + ((lane >> 4) & 3) * 8 + j;
    *(unsigned short*)(ws + OFF_GRUW + (size_t)e * 2) = f2bf(gru_whh[n * HH + k]);
    return;
  }
  e -= 49152;
  if (e < 12288) {  // one-hot table: emb[k]@gru_wih[n] + bih[n]
    int j = e & 7, lane = (e >> 3) & 63, ct = e >> 9;
    int n = ct * 16 + (lane & 15);
    int k = ((lane >> 4) & 3) * 8 + j;
    float v = 0.0f;
    if (k < VV) {
      float s0 = 0.f, s1 = 0.f, s2 = 0.f, s3 = 0.f;
      const float* ep = emb + k * EE;
      const float* wp = gru_wih + n * EE;
#pragma unroll 5
      for (int m = 0; m < EE; m += 4) {
        s0 += ep[m] * wp[m];     s1 += ep[m + 1] * wp[m + 1];
        s2 += ep[m + 2] * wp[m + 2]; s3 += ep[m + 3] * wp[m + 3];
      }
      v = gru_bih[n] + ((s0 + s1) + (s2 + s3));
    }
    *(unsigned short*)(ws + OFF_TBL + (size_t)e * 2) = f2bf(v);
    return;
  }
  e -= 12288;
  if (e < 114688) {  // LSTM fused W: row=112g+c, K=[y 0..127 | h 0..127]
    int j = e & 7, lane = (e >> 3) & 63, kc = (e >> 9) & 7, ct = e >> 12;
    int row = ct * 16 + (lane & 15);
    int g = row / 112, c = row % 112;
    int q = (lane >> 4) & 3;
    float v = 0.0f;
    if (c < EE) {
      if (kc < 4) {
        int k = kc * 32 + q * 8 + j;
        v = lstm_wih[(g * EE + c) * HH + k];
      } else {
        int k = (kc - 4) * 32 + q * 8 + j;
        if (k < EE) v = lstm_whh[(g * EE + c) * EE + k];
      }
    }
    *(unsigned short*)(ws + OFF_LSTMW + (size_t)e * 2) = f2bf(v);
    return;
  }
  e -= 114688;
  if (e < 4096) {  // out_w (23x100 -> 32x128)
    int j = e & 7, lane = (e >> 3) & 63, kc = (e >> 9) & 3, ct = e >> 11;
    int n = ct * 16 + (lane & 15);
    int k = kc * 32 + ((lane >> 4) & 3) * 8 + j;
    float v = (n < VV && k < EE) ? out_w[n * EE + k] : 0.0f;
    *(unsigned short*)(ws + OFF_OUTW + (size_t)e * 2) = f2bf(v);
    return;
  }
  e -= 4096;
  if (e < 8192) {  // fc_z_w (128x64)
    int j = e & 7, lane = (e >> 3) & 63, kc = (e >> 9) & 1, ct = e >> 10;
    int n = ct * 16 + (lane & 15);
    int k = kc * 32 + ((lane >> 4) & 3) * 8 + j;
    *(unsigned short*)(ws + OFF_FCZW + (size_t)e * 2) = f2bf(fc_z_w[n * LL + k]);
    return;
  }
  e -= 8192;
  if (e < 448) {  // fused LSTM bias
    int g = e / 112, c = e % 112;
    float v = (c < EE) ? (lstm_bih[g * EE + c] + lstm_bhh[g * EE + c]) : 0.0f;
    *(float*)(ws + OFF_LBIAS + (size_t)e * 4) = v;
  }
}

// =====================================================================
// K1: GRU scan. 256 blocks x 512 thr (8 waves), 32 rows/block
// (2 sub-btiles of 16). Wave wv owns cols [16wv,16wv+16) of r,z,n.
// Weights pinned under a 256-reg budget (launch_bounds(512,2)).
// h dbuf in LDS A-frag layout; y(t-1) exported early each phase.
// =====================================================================
__global__ __launch_bounds__(512, 2) void gru_kernel(
    const float* __restrict__ z, const int* __restrict__ x_in,
    const float* __restrict__ fc_z_b, const float* __restrict__ gru_bhh,
    const unsigned short* __restrict__ gruw, const unsigned short* __restrict__ tbl,
    const unsigned short* __restrict__ fczw, unsigned short* __restrict__ yout)
{
  __shared__ unsigned short hfrag[2][2][2048];   // [buf][sub][4 kc * 512]
  __shared__ unsigned char idx_lds[TT * 32];
  const int tid  = threadIdx.x;
  const int wv   = tid >> 6;
  const int lane = tid & 63;
  const int l15  = lane & 15;
  const int q    = (lane >> 4) & 3;
  const int blk  = blockIdx.x;      // 0..255

  for (int i = tid; i < TT * 32; i += 512) {
    int t = i >> 5, r = i & 31;
    idx_lds[i] = (unsigned char)x_in[(blk * 32 + r) * TT + t];
  }

  // stationary weight fragments — loaded once, pinned
  bf16x8 gw[3][4], tw[3];
#pragma unroll
  for (int g = 0; g < 3; g++) {
    int ct = g * 8 + wv;
#pragma unroll
    for (int kc = 0; kc < 4; kc++) {
      gw[g][kc] = *(const bf16x8*)(gruw + (size_t)(ct * 4 + kc) * 512 + lane * 8);
      force_frag(gw[g][kc]);
    }
    tw[g] = *(const bf16x8*)(tbl + (size_t)ct * 512 + lane * 8);
    force_frag(tw[g]);
  }
  const int col = wv * 16 + l15;
  const float b_r = gru_bhh[0 * HH + col];
  const float b_z = gru_bhh[1 * HH + col];
  const float b_n = gru_bhh[2 * HH + col];
  const int wbase = (col >> 5) * 512 + ((col >> 3) & 3) * 128 + (col & 7);

  // h0 = tanh(z @ fc_z_w^T + fc_z_b) via MFMA, per sub-btile
  float h[2][4];
  {
    bf16x8 fw0 = *(const bf16x8*)(fczw + (size_t)(wv * 2 + 0) * 512 + lane * 8);
    bf16x8 fw1 = *(const bf16x8*)(fczw + (size_t)(wv * 2 + 1) * 512 + lane * 8);
    float fzb = fc_z_b[col];
#pragma unroll
    for (int s = 0; s < 2; s++) {
      const float* zp = z + (size_t)(blk * 32 + s * 16 + l15) * LL + q * 8;
      f32x4 z0 = *(const f32x4*)(zp);
      f32x4 z1 = *(const f32x4*)(zp + 4);
      f32x4 z2 = *(const f32x4*)(zp + 32);
      f32x4 z3 = *(const f32x4*)(zp + 36);
      bf16x8 za0, za1;
#pragma unroll
      for (int j = 0; j < 4; j++) {
        za0[j]     = (short)f2bf(z0[j]);
        za0[4 + j] = (short)f2bf(z1[j]);
        za1[j]     = (short)f2bf(z2[j]);
        za1[4 + j] = (short)f2bf(z3[j]);
      }
      f32x4 acc = {fzb, fzb, fzb, fzb};
      acc = MFMA(za0, fw0, acc);
      acc = MFMA(za1, fw1, acc);
#pragma unroll
      for (int i = 0; i < 4; i++) {
        h[s][i] = tanh_(acc[i]);
        hfrag[0][s][wbase + (q * 4 + i) * 8] = f2bf_fast(h[s][i]);
      }
    }
  }
  __syncthreads();

  const int xs = wv >> 2, xk = wv & 3;   // this wave's export (sub, kc)
  int cur = 0;
  for (int t = 0; t < TT; t++) {
    // export y(t-1) EARLY (full phase of slack before the barrier drain)
    if (t > 0) {
      bf16x8 yv = *(const bf16x8*)&hfrag[cur][xs][xk * 512 + lane * 8];
      *(bf16x8*)(yout + ((size_t)((blk * 2 + xs) * TT + (t - 1)) * 4 + xk) * 512 + lane * 8) = yv;
    }
    int nb = cur ^ 1;
#pragma unroll
    for (int s = 0; s < 2; s++) {
      int iv = idx_lds[t * 32 + s * 16 + l15];
      bf16x8 oh;
#pragma unroll
      for (int j = 0; j < 8; j++)
        oh[j] = (short)((iv == q * 8 + j) ? 0x3F80 : 0);

      f32x4 ar  = {b_r, b_r, b_r, b_r};
      f32x4 az  = {b_z, b_z, b_z, b_z};
      f32x4 ahn = {b_n, b_n, b_n, b_n};
      f32x4 axn = {0.0f, 0.0f, 0.0f, 0.0f};
      ar  = MFMA(oh, tw[0], ar);
      az  = MFMA(oh, tw[1], az);
      axn = MFMA(oh, tw[2], axn);

      bf16x8 a[4];
#pragma unroll
      for (int kc = 0; kc < 4; kc++)
        a[kc] = *(const bf16x8*)&hfrag[cur][s][kc * 512 + lane * 8];
#pragma unroll
      for (int kc = 0; kc < 4; kc++) {
        ar  = MFMA(a[kc], gw[0][kc], ar);
        az  = MFMA(a[kc], gw[1][kc], az);
        ahn = MFMA(a[kc], gw[2][kc], ahn);
      }
#pragma unroll
      for (int i = 0; i < 4; i++) {
        float r  = sigm(ar[i]);
        float zg = sigm(az[i]);
        float n  = tanh_(__builtin_fmaf(r, ahn[i], axn[i]));
        h[s][i] = __builtin_fmaf(zg, h[s][i] - n, n);
        hfrag[nb][s][wbase + (q * 4 + i) * 8] = f2bf_fast(h[s][i]);
      }
    }
    __syncthreads();
    cur = nb;
  }
  // tail: export y(TT-1)
  {
    bf16x8 yv = *(const bf16x8*)&hfrag[cur][xs][xk * 512 + lane * 8];
    *(bf16x8*)(yout + ((size_t)((blk * 2 + xs) * TT + (TT - 1)) * 4 + xk) * 512 + lane * 8) = yv;
  }
}

// =====================================================================
// K2: LSTM scan + in-kernel logits. 256 blocks x 512 thr (8 waves),
// 32 rows/block (2 sub-btiles). Waves 0-6: fused K=256 (y-half from
// global ya, h-half from LDS hbuf) -> 32 MFMA per sub-btile per phase,
// no Pbuf, one barrier/phase. Wave 7: logits 1 phase behind, reading
// hbuf directly (h never exported). Weights pinned (256-reg budget).
// =====================================================================
__global__ __launch_bounds__(512, 2) void lstm_kernel(
    const unsigned short* __restrict__ lstmw, const float* __restrict__ lbias,
    const unsigned short* __restrict__ ybuf,
    const float* __restrict__ out_b, const unsigned short* __restrict__ outw,
    float* __restrict__ out)
{
  __shared__ unsigned short hbuf[2][2][2048];   // [buf][sub][4 kc * 512]
  const int tid  = threadIdx.x;
  const int wv   = tid >> 6;        // 0..7
  const int lane = tid & 63;
  const int l15  = lane & 15;
  const int q    = (lane >> 4) & 3;
  const int blk  = blockIdx.x;      // 0..255

  for (int i = tid; i < 2 * 2 * 2048; i += 512)
    ((unsigned short*)hbuf)[i] = 0;

  if (wv < 7) {
    // ------------- fused compute waves (col-tile wv) -------------
    bf16x8 lw[4][8];
#pragma unroll
    for (int g = 0; g < 4; g++)
#pragma unroll
      for (int kc = 0; kc < 8; kc++) {
        lw[g][kc] = *(const bf16x8*)(lstmw + (size_t)((g * 7 + wv) * 8 + kc) * 512 + lane * 8);
        force_frag(lw[g][kc]);
      }
    const int col = wv * 16 + l15;
    float b[4];
#pragma unroll
    for (int g = 0; g < 4; g++) b[g] = lbias[g * 112 + col];
    const int wbase = (col >> 5) * 512 + ((col >> 3) & 3) * 128 + (col & 7);
    float c[2][4] = {{0, 0, 0, 0}, {0, 0, 0, 0}};
    __syncthreads();

    for (int p = 0; p <= TT; p++) {
      if (p < TT) {
        // issue y A-frag loads for both sub-btiles up front
        bf16x8 ya[2][4];
#pragma unroll
        for (int s = 0; s < 2; s++)
#pragma unroll
          for (int kc = 0; kc < 4; kc++)
            ya[s][kc] = *(const bf16x8*)(ybuf + ((size_t)((blk * 2 + s) * TT + p) * 4 + kc) * 512 + lane * 8);

#pragma unroll
        for (int s = 0; s < 2; s++) {
          bf16x8 ha[4];
#pragma unroll
          for (int kc = 0; kc < 4; kc++)
            ha[kc] = *(const bf16x8*)&hbuf[p & 1][s][kc * 512 + lane * 8];
          f32x4 ai = {b[0], b[0], b[0], b[0]};
          f32x4 af = {b[1], b[1], b[1], b[1]};
          f32x4 ag = {b[2], b[2], b[2], b[2]};
          f32x4 ao = {b[3], b[3], b[3], b[3]};
          // h-half first (LDS operands ready; covers ya load latency)
#pragma unroll
          for (int kc = 0; kc < 4; kc++) {
            ai = MFMA(ha[kc], lw[0][kc + 4], ai);
            af = MFMA(ha[kc], lw[1][kc + 4], af);
            ag = MFMA(ha[kc], lw[2][kc + 4], ag);
            ao = MFMA(ha[kc], lw[3][kc + 4], ao);
          }
#pragma unroll
          for (int kc = 0; kc < 4; kc++) {
            ai = MFMA(ya[s][kc], lw[0][kc], ai);
            af = MFMA(ya[s][kc], lw[1][kc], af);
            ag = MFMA(ya[s][kc], lw[2][kc], ag);
            ao = MFMA(ya[s][kc], lw[3][kc], ao);
          }
#pragma unroll
          for (int i = 0; i < 4; i++) {
            float ii = sigm(ai[i]), ff = sigm(af[i]);
            float gg = tanh_(ag[i]), oo = sigm(ao[i]);
            float cn = __builtin_fmaf(ff, c[s][i], ii * gg);
            c[s][i] = cn;
            hbuf[(p + 1) & 1][s][wbase + (q * 4 + i) * 8] = f2bf_fast(oo * tanh_(cn));
          }
        }
      }
      __syncthreads();
    }
  } else {
    // ------------- logits wave (1 phase behind) -------------
    bf16x8 ow[2][4];
#pragma unroll
    for (int ct = 0; ct < 2; ct++)
#pragma unroll
      for (int kc = 0; kc < 4; kc++) {
        ow[ct][kc] = *(const bf16x8*)(outw + (size_t)(ct * 4 + kc) * 512 + lane * 8);
        force_frag(ow[ct][kc]);
      }
    float ob[2];
#pragma unroll
    for (int ct = 0; ct < 2; ct++) {
      int cv = ct * 16 + l15;
      ob[ct] = (cv < VV) ? out_b[cv] : 0.0f;
    }
    __syncthreads();

    for (int p = 0; p <= TT; p++) {
      if (p >= 1) {
        const int t = p - 1;
#pragma unroll
        for (int s = 0; s < 2; s++) {
          bf16x8 ha[4];
#pragma unroll
          for (int kc = 0; kc < 4; kc++)
            ha[kc] = *(const bf16x8*)&hbuf[p & 1][s][kc * 512 + lane * 8];
#pragma unroll
          for (int ct = 0; ct < 2; ct++) {
            f32x4 acc = {ob[ct], ob[ct], ob[ct], ob[ct]};
#pragma unroll
            for (int kc = 0; kc < 4; kc++)
              acc = MFMA(ha[kc], ow[ct][kc], acc);
            int cv = ct * 16 + l15;
            if (cv < VV) {
#pragma unroll
              for (int i = 0; i < 4; i++) {
                int rowg = blk * 32 + s * 16 + q * 4 + i;
                out[((size_t)rowg * TT + t) * VV + cv] = acc[i];
              }
            }
          }
        }
      }
      __syncthreads();
    }
  }
}

extern "C" void kernel_launch(void* const* d_in, const int* in_sizes, int n_in,
                              void* d_out, int out_size, void* d_ws, size_t ws_size,
                              hipStream_t stream) {
  (void)in_sizes; (void)n_in; (void)out_size; (void)ws_size;
  const float* z        = (const float*)d_in[0];
  const int*   x_in     = (const int*)  d_in[1];
  const float* emb      = (const float*)d_in[2];
  const float* fc_z_w   = (const float*)d_in[3];
  const float* fc_z_b   = (const float*)d_in[4];
  const float* gru_wih  = (const float*)d_in[5];
  const float* gru_whh  = (const float*)d_in[6];
  const float* gru_bih  = (const float*)d_in[7];
  const float* gru_bhh  = (const float*)d_in[8];
  const float* lstm_wih = (const float*)d_in[9];
  const float* lstm_whh = (const float*)d_in[10];
  const float* lstm_bih = (const float*)d_in[11];
  const float* lstm_bhh = (const float*)d_in[12];
  const float* out_w    = (const float*)d_in[13];
  const float* out_b    = (const float*)d_in[14];
  char*  ws  = (char*)d_ws;
  float* out = (float*)d_out;

  const unsigned short* gruw  = (const unsigned short*)(ws + OFF_GRUW);
  const unsigned short* tblp  = (const unsigned short*)(ws + OFF_TBL);
  const unsigned short* lstmw = (const unsigned short*)(ws + OFF_LSTMW);
  const unsigned short* outw  = (const unsigned short*)(ws + OFF_OUTW);
  const unsigned short* fczw  = (const unsigned short*)(ws + OFF_FCZW);
  const float*          lbias = (const float*)(ws + OFF_LBIAS);
  unsigned short*       ybuf  = (unsigned short*)(ws + OFF_Y);

  prep_kernel<<<738, 256, 0, stream>>>(emb, fc_z_w, gru_wih, gru_whh, gru_bih,
                                       lstm_wih, lstm_whh, lstm_bih, lstm_bhh,
                                       out_w, ws);
  gru_kernel<<<256, 512, 0, stream>>>(z, x_in, fc_z_b, gru_bhh,
                                      gruw, tblp, fczw, ybuf);
  lstm_kernel<<<256, 512, 0, stream>>>(lstmw, lbias, ybuf, out_b, outw, out);
}

// Round 7
// 190.074 us; speedup vs baseline: 1.1005x; 1.0937x over previous
//
#include <hip/hip_runtime.h>
#include <stdint.h>
#include <stddef.h>

// Problem dims (fixed by reference)
#define BB 8192
#define TT 26
#define VV 23
#define EE 100
#define HH 128
#define LL 64

typedef __attribute__((ext_vector_type(8))) short bf16x8;  // 8 bf16 = 4 VGPRs
typedef __attribute__((ext_vector_type(4))) float f32x4;   // MFMA 16x16 C/D

#define MFMA(a, b, c) __builtin_amdgcn_mfma_f32_16x16x32_bf16((a), (b), (c), 0, 0, 0)

// ---------------- workspace layout (bytes) ----------------
#define OFF_GRUW   0ull                  // GRU Whh B-frags: 24ct*4kc*1024
#define OFF_TBL    98304ull              // one-hot table B-frags: 24ct*1024
#define OFF_LSTMW  122880ull             // LSTM fused W B-frags: 28ct*8kc*1024 (kc0-3=y, kc4-7=h)
#define OFF_OUTW   352256ull             // out_w B-frags: 2ct*4kc*1024
#define OFF_FCZW   360448ull             // fc_z_w B-frags: 8ct*2kc*1024
#define OFF_LBIAS  376832ull             // fused LSTM bias 4*112 fp32
#define OFF_Y      379904ull             // y A-frags: 512 btile * 26 t * 4 kc * 1024B

__device__ __forceinline__ void force_frag(bf16x8& v) { asm volatile("" : "+v"(v)); }

// Exact RNE (prep only)
__device__ __forceinline__ unsigned short f2bf(float f) {
  union { float f; unsigned u; } v; v.f = f;
  unsigned u = v.u;
  return (unsigned short)((u + 0x7FFFu + ((u >> 16) & 1u)) >> 16);
}
// Fast in-loop convert (round-half-up)
__device__ __forceinline__ unsigned short f2bf_fast(float f) {
  union { float f; unsigned u; } v; v.f = f;
  return (unsigned short)((v.u + 0x8000u) >> 16);
}
#define LOG2E 1.4426950408889634f
__device__ __forceinline__ float sigm(float x) {
  return __builtin_amdgcn_rcpf(1.0f + __builtin_amdgcn_exp2f(-x * LOG2E));
}
__device__ __forceinline__ float tanh_(float x) {
  return __builtin_fmaf(-2.0f,
      __builtin_amdgcn_rcpf(1.0f + __builtin_amdgcn_exp2f(x * (2.0f * LOG2E))), 1.0f);
}

// =====================================================================
// K0a: one-hot table build, LDS-staged (the old per-thread 100-MAC
// gathered dot at 5% occupancy was a suspected ~40 us hidden cost).
// 24 blocks (one per ct) x 512 thr; emb + 16 wih rows staged in LDS.
// tbl[e], e = ct*512 + lane*8 + j: n = ct*16+(lane&15), k = q*8+j.
// =====================================================================
__global__ __launch_bounds__(512) void prep_table_kernel(
    const float* __restrict__ emb, const float* __restrict__ gru_wih,
    const float* __restrict__ gru_bih, char* __restrict__ ws)
{
  __shared__ float emb_s[VV * EE];      // 9200 B
  __shared__ float wih_s[16 * EE];      // 6400 B
  __shared__ float bih_s[16];
  const int tid = threadIdx.x;
  const int ct  = blockIdx.x;           // 0..23
  const int n0  = ct * 16;

  for (int i = tid; i < VV * EE; i += 512) emb_s[i] = emb[i];
  for (int i = tid; i < 16 * EE; i += 512) wih_s[i] = gru_wih[n0 * EE + i];
  if (tid < 16) bih_s[tid] = gru_bih[n0 + tid];
  __syncthreads();

  const int j    = tid & 7;
  const int lane = (tid >> 3) & 63;
  const int n16  = lane & 15;
  const int k    = ((lane >> 4) & 3) * 8 + j;
  float v = 0.0f;
  if (k < VV) {
    const float* ep = emb_s + k * EE;
    const float* wp = wih_s + n16 * EE;
    float s0 = 0.f, s1 = 0.f, s2 = 0.f, s3 = 0.f;
#pragma unroll 5
    for (int m = 0; m < EE; m += 4) {
      s0 += ep[m] * wp[m];         s1 += ep[m + 1] * wp[m + 1];
      s2 += ep[m + 2] * wp[m + 2]; s3 += ep[m + 3] * wp[m + 3];
    }
    v = bih_s[n16] + ((s0 + s1) + (s2 + s3));
  }
  *(unsigned short*)(ws + OFF_TBL + (size_t)(ct * 512 + tid) * 2) = f2bf(v);
}

// =====================================================================
// K0b: remaining weight swizzles (all coalesced single-load threads).
// =====================================================================
__global__ __launch_bounds__(256) void prep_main_kernel(
    const float* __restrict__ fc_z_w, const float* __restrict__ gru_whh,
    const float* __restrict__ lstm_wih, const float* __restrict__ lstm_whh,
    const float* __restrict__ lstm_bih, const float* __restrict__ lstm_bhh,
    const float* __restrict__ out_w, char* __restrict__ ws)
{
  int e = blockIdx.x * 256 + threadIdx.x;

  if (e < 49152) {  // GRU Whh (384x128)
    int j = e & 7, lane = (e >> 3) & 63, kc = (e >> 9) & 3, ct = e >> 11;
    int n = ct * 16 + (lane & 15);
    int k = kc * 32 + ((lane >> 4) & 3) * 8 + j;
    *(unsigned short*)(ws + OFF_GRUW + (size_t)e * 2) = f2bf(gru_whh[n * HH + k]);
    return;
  }
  e -= 49152;
  if (e < 114688) {  // LSTM fused W: row=112g+c, K=[y 0..127 | h 0..127]
    int j = e & 7, lane = (e >> 3) & 63, kc = (e >> 9) & 7, ct = e >> 12;
    int row = ct * 16 + (lane & 15);
    int g = row / 112, c = row % 112;
    int q = (lane >> 4) & 3;
    float v = 0.0f;
    if (c < EE) {
      if (kc < 4) {
        int k = kc * 32 + q * 8 + j;
        v = lstm_wih[(g * EE + c) * HH + k];
      } else {
        int k = (kc - 4) * 32 + q * 8 + j;
        if (k < EE) v = lstm_whh[(g * EE + c) * EE + k];
      }
    }
    *(unsigned short*)(ws + OFF_LSTMW + (size_t)e * 2) = f2bf(v);
    return;
  }
  e -= 114688;
  if (e < 4096) {  // out_w (23x100 -> 32x128)
    int j = e & 7, lane = (e >> 3) & 63, kc = (e >> 9) & 3, ct = e >> 11;
    int n = ct * 16 + (lane & 15);
    int k = kc * 32 + ((lane >> 4) & 3) * 8 + j;
    float v = (n < VV && k < EE) ? out_w[n * EE + k] : 0.0f;
    *(unsigned short*)(ws + OFF_OUTW + (size_t)e * 2) = f2bf(v);
    return;
  }
  e -= 4096;
  if (e < 8192) {  // fc_z_w (128x64)
    int j = e & 7, lane = (e >> 3) & 63, kc = (e >> 9) & 1, ct = e >> 10;
    int n = ct * 16 + (lane & 15);
    int k = kc * 32 + ((lane >> 4) & 3) * 8 + j;
    *(unsigned short*)(ws + OFF_FCZW + (size_t)e * 2) = f2bf(fc_z_w[n * LL + k]);
    return;
  }
  e -= 8192;
  if (e < 448) {  // fused LSTM bias
    int g = e / 112, c = e % 112;
    float v = (c < EE) ? (lstm_bih[g * EE + c] + lstm_bhh[g * EE + c]) : 0.0f;
    *(float*)(ws + OFF_LBIAS + (size_t)e * 4) = v;
  }
}

// =====================================================================
// K1: GRU scan — proven R4 shape: 512 blocks x 512 thr (8 waves),
// 16 rows/block, (512,4) so 2 blocks/CU can co-schedule.
// h dbuf in LDS A-frag layout; y(t-1) exported early each phase.
// =====================================================================
__global__ __launch_bounds__(512, 4) void gru_kernel(
    const float* __restrict__ z, const int* __restrict__ x_in,
    const float* __restrict__ fc_z_b, const float* __restrict__ gru_bhh,
    const unsigned short* __restrict__ gruw, const unsigned short* __restrict__ tbl,
    const unsigned short* __restrict__ fczw, unsigned short* __restrict__ yout)
{
  __shared__ unsigned short hfrag[2][2048];
  __shared__ unsigned char idx_lds[TT * 16];
  const int tid  = threadIdx.x;
  const int wv   = tid >> 6;
  const int lane = tid & 63;
  const int l15  = lane & 15;
  const int q    = (lane >> 4) & 3;
  const int blk  = blockIdx.x;

  for (int i = tid; i < TT * 16; i += 512) {
    int t = i >> 4, r = i & 15;
    idx_lds[i] = (unsigned char)x_in[(blk * 16 + r) * TT + t];
  }

  bf16x8 gw[3][4], tw[3];
#pragma unroll
  for (int g = 0; g < 3; g++) {
    int ct = g * 8 + wv;
#pragma unroll
    for (int kc = 0; kc < 4; kc++) {
      gw[g][kc] = *(const bf16x8*)(gruw + (size_t)(ct * 4 + kc) * 512 + lane * 8);
      force_frag(gw[g][kc]);
    }
    tw[g] = *(const bf16x8*)(tbl + (size_t)ct * 512 + lane * 8);
    force_frag(tw[g]);
  }
  const int col = wv * 16 + l15;
  const float b_r = gru_bhh[0 * HH + col];
  const float b_z = gru_bhh[1 * HH + col];
  const float b_n = gru_bhh[2 * HH + col];
  const int wbase = (col >> 5) * 512 + ((col >> 3) & 3) * 128 + (col & 7);

  float h[4];
  {
    bf16x8 fw0 = *(const bf16x8*)(fczw + (size_t)(wv * 2 + 0) * 512 + lane * 8);
    bf16x8 fw1 = *(const bf16x8*)(fczw + (size_t)(wv * 2 + 1) * 512 + lane * 8);
    const float* zp = z + (size_t)(blk * 16 + l15) * LL + q * 8;
    f32x4 z0 = *(const f32x4*)(zp);
    f32x4 z1 = *(const f32x4*)(zp + 4);
    f32x4 z2 = *(const f32x4*)(zp + 32);
    f32x4 z3 = *(const f32x4*)(zp + 36);
    bf16x8 za0, za1;
#pragma unroll
    for (int j = 0; j < 4; j++) {
      za0[j]     = (short)f2bf(z0[j]);
      za0[4 + j] = (short)f2bf(z1[j]);
      za1[j]     = (short)f2bf(z2[j]);
      za1[4 + j] = (short)f2bf(z3[j]);
    }
    float fzb = fc_z_b[col];
    f32x4 acc = {fzb, fzb, fzb, fzb};
    acc = MFMA(za0, fw0, acc);
    acc = MFMA(za1, fw1, acc);
#pragma unroll
    for (int i = 0; i < 4; i++) {
      h[i] = tanh_(acc[i]);
      hfrag[0][wbase + (q * 4 + i) * 8] = f2bf_fast(h[i]);
    }
  }
  __syncthreads();

  int cur = 0;
  for (int t = 0; t < TT; t++) {
    if (t > 0 && wv < 4) {
      bf16x8 yv = *(const bf16x8*)((const char*)hfrag[cur] + wv * 1024 + lane * 16);
      *(bf16x8*)(yout + ((size_t)(blk * TT + (t - 1)) * 4 + wv) * 512 + lane * 8) = yv;
    }
    int iv = idx_lds[t * 16 + l15];
    bf16x8 oh;
#pragma unroll
    for (int j = 0; j < 8; j++)
      oh[j] = (short)((iv == q * 8 + j) ? 0x3F80 : 0);

    f32x4 ar  = {b_r, b_r, b_r, b_r};
    f32x4 az  = {b_z, b_z, b_z, b_z};
    f32x4 ahn = {b_n, b_n, b_n, b_n};
    f32x4 axn = {0.0f, 0.0f, 0.0f, 0.0f};
    ar  = MFMA(oh, tw[0], ar);
    az  = MFMA(oh, tw[1], az);
    axn = MFMA(oh, tw[2], axn);

    bf16x8 a[4];
#pragma unroll
    for (int kc = 0; kc < 4; kc++)
      a[kc] = *(const bf16x8*)((const char*)hfrag[cur] + kc * 1024 + lane * 16);
#pragma unroll
    for (int kc = 0; kc < 4; kc++) {
      ar  = MFMA(a[kc], gw[0][kc], ar);
      az  = MFMA(a[kc], gw[1][kc], az);
      ahn = MFMA(a[kc], gw[2][kc], ahn);
    }

    int nb = cur ^ 1;
#pragma unroll
    for (int i = 0; i < 4; i++) {
      float r  = sigm(ar[i]);
      float zg = sigm(az[i]);
      float n  = tanh_(__builtin_fmaf(r, ahn[i], axn[i]));
      h[i] = __builtin_fmaf(zg, h[i] - n, n);
      hfrag[nb][wbase + (q * 4 + i) * 8] = f2bf_fast(h[i]);
    }
    __syncthreads();
    cur = nb;
  }
  if (wv < 4) {
    bf16x8 yv = *(const bf16x8*)((const char*)hfrag[cur] + wv * 1024 + lane * 16);
    *(bf16x8*)(yout + ((size_t)(blk * TT + (TT - 1)) * 4 + wv) * 512 + lane * 8) = yv;
  }
}

// =====================================================================
// K2: LSTM scan + in-kernel logits, SOFTWARE-PIPELINED y-half.
// 256 blocks x 512 thr (8 waves), 32 rows (2 subs). Compute wave per
// phase p: h-half MFMA (into carried yacc) -> gates(p) -> h write ->
// ya(p+1) load + y-half MFMA for p+1 (fills MFMA pipe under the gate
// tail; ya latency off the critical path). Wave 7: logits 1 phase back.
// =====================================================================
__global__ __launch_bounds__(512, 2) void lstm_kernel(
    const unsigned short* __restrict__ lstmw, const float* __restrict__ lbias,
    const unsigned short* __restrict__ ybuf,
    const float* __restrict__ out_b, const unsigned short* __restrict__ outw,
    float* __restrict__ out)
{
  __shared__ unsigned short hbuf[2][2][2048];
  const int tid  = threadIdx.x;
  const int wv   = tid >> 6;        // 0..7
  const int lane = tid & 63;
  const int l15  = lane & 15;
  const int q    = (lane >> 4) & 3;
  const int blk  = blockIdx.x;      // 0..255

  for (int i = tid; i < 2 * 2 * 2048; i += 512)
    ((unsigned short*)hbuf)[i] = 0;

  if (wv < 7) {
    bf16x8 lw[4][8];
#pragma unroll
    for (int g = 0; g < 4; g++)
#pragma unroll
      for (int kc = 0; kc < 8; kc++) {
        lw[g][kc] = *(const bf16x8*)(lstmw + (size_t)((g * 7 + wv) * 8 + kc) * 512 + lane * 8);
        force_frag(lw[g][kc]);
      }
    const int col = wv * 16 + l15;
    float b[4];
#pragma unroll
    for (int g = 0; g < 4; g++) b[g] = lbias[g * 112 + col];
    const int wbase = (col >> 5) * 512 + ((col >> 3) & 3) * 128 + (col & 7);
    float c[2][4] = {{0, 0, 0, 0}, {0, 0, 0, 0}};
    __syncthreads();                                   // barrier #0

    // prologue: yacc = bias + y-half(step 0)
    f32x4 yacc[2][4];
#pragma unroll
    for (int s = 0; s < 2; s++) {
      bf16x8 ya[4];
#pragma unroll
      for (int kc = 0; kc < 4; kc++)
        ya[kc] = *(const bf16x8*)(ybuf + ((size_t)((blk * 2 + s) * TT + 0) * 4 + kc) * 512 + lane * 8);
#pragma unroll
      for (int g = 0; g < 4; g++) yacc[s][g] = (f32x4){b[g], b[g], b[g], b[g]};
#pragma unroll
      for (int kc = 0; kc < 4; kc++) {
        yacc[s][0] = MFMA(ya[kc], lw[0][kc], yacc[s][0]);
        yacc[s][1] = MFMA(ya[kc], lw[1][kc], yacc[s][1]);
        yacc[s][2] = MFMA(ya[kc], lw[2][kc], yacc[s][2]);
        yacc[s][3] = MFMA(ya[kc], lw[3][kc], yacc[s][3]);
      }
    }

    for (int p = 0; p < TT; p++) {
      const int pn = (p + 1 < TT) ? (p + 1) : (TT - 1);
      // h-half: accumulate into carried yacc (pre-acts for step p)
#pragma unroll
      for (int s = 0; s < 2; s++) {
        bf16x8 ha[4];
#pragma unroll
        for (int kc = 0; kc < 4; kc++)
          ha[kc] = *(const bf16x8*)&hbuf[p & 1][s][kc * 512 + lane * 8];
#pragma unroll
        for (int kc = 0; kc < 4; kc++) {
          yacc[s][0] = MFMA(ha[kc], lw[0][kc + 4], yacc[s][0]);
          yacc[s][1] = MFMA(ha[kc], lw[1][kc + 4], yacc[s][1]);
          yacc[s][2] = MFMA(ha[kc], lw[2][kc + 4], yacc[s][2]);
          yacc[s][3] = MFMA(ha[kc], lw[3][kc + 4], yacc[s][3]);
        }
      }
      // issue next-step ya loads (latency hidden under gates)
      bf16x8 yan[2][4];
#pragma unroll
      for (int s = 0; s < 2; s++)
#pragma unroll
        for (int kc = 0; kc < 4; kc++)
          yan[s][kc] = *(const bf16x8*)(ybuf + ((size_t)((blk * 2 + s) * TT + pn) * 4 + kc) * 512 + lane * 8);
      // gates for step p; write h(p) into hbuf[(p+1)&1]
#pragma unroll
      for (int s = 0; s < 2; s++) {
#pragma unroll
        for (int i = 0; i < 4; i++) {
          float ii = sigm(yacc[s][0][i]), ff = sigm(yacc[s][1][i]);
          float gg = tanh_(yacc[s][2][i]), oo = sigm(yacc[s][3][i]);
          float cn = __builtin_fmaf(ff, c[s][i], ii * gg);
          c[s][i] = cn;
          hbuf[(p + 1) & 1][s][wbase + (q * 4 + i) * 8] = f2bf_fast(oo * tanh_(cn));
        }
      }
      // y-half for step p+1 (MFMA pipe fills while other waves' gates run)
#pragma unroll
      for (int s = 0; s < 2; s++) {
#pragma unroll
        for (int g = 0; g < 4; g++) yacc[s][g] = (f32x4){b[g], b[g], b[g], b[g]};
#pragma unroll
        for (int kc = 0; kc < 4; kc++) {
          yacc[s][0] = MFMA(yan[s][kc], lw[0][kc], yacc[s][0]);
          yacc[s][1] = MFMA(yan[s][kc], lw[1][kc], yacc[s][1]);
          yacc[s][2] = MFMA(yan[s][kc], lw[2][kc], yacc[s][2]);
          yacc[s][3] = MFMA(yan[s][kc], lw[3][kc], yacc[s][3]);
        }
      }
      __syncthreads();                                 // 26 barriers
    }
    __syncthreads();                                   // match logits' 27th
  } else {
    // ------------- logits wave (1 phase behind) -------------
    bf16x8 ow[2][4];
#pragma unroll
    for (int ct = 0; ct < 2; ct++)
#pragma unroll
      for (int kc = 0; kc < 4; kc++) {
        ow[ct][kc] = *(const bf16x8*)(outw + (size_t)(ct * 4 + kc) * 512 + lane * 8);
        force_frag(ow[ct][kc]);
      }
    float ob[2];
#pragma unroll
    for (int ct = 0; ct < 2; ct++) {
      int cv = ct * 16 + l15;
      ob[ct] = (cv < VV) ? out_b[cv] : 0.0f;
    }
    __syncthreads();                                   // barrier #0

    for (int p = 0; p <= TT; p++) {
      if (p >= 1) {
        const int t = p - 1;
#pragma unroll
        for (int s = 0; s < 2; s++) {
          bf16x8 ha[4];
#pragma unroll
          for (int kc = 0; kc < 4; kc++)
            ha[kc] = *(const bf16x8*)&hbuf[p & 1][s][kc * 512 + lane * 8];
#pragma unroll
          for (int ct = 0; ct < 2; ct++) {
            f32x4 acc = {ob[ct], ob[ct], ob[ct], ob[ct]};
#pragma unroll
            for (int kc = 0; kc < 4; kc++)
              acc = MFMA(ha[kc], ow[ct][kc], acc);
            int cv = ct * 16 + l15;
            if (cv < VV) {
#pragma unroll
              for (int i = 0; i < 4; i++) {
                int rowg = blk * 32 + s * 16 + q * 4 + i;
                out[((size_t)rowg * TT + t) * VV + cv] = acc[i];
              }
            }
          }
        }
      }
      __syncthreads();                                 // 27 barriers
    }
  }
}

extern "C" void kernel_launch(void* const* d_in, const int* in_sizes, int n_in,
                              void* d_out, int out_size, void* d_ws, size_t ws_size,
                              hipStream_t stream) {
  (void)in_sizes; (void)n_in; (void)out_size; (void)ws_size;
  const float* z        = (const float*)d_in[0];
  const int*   x_in     = (const int*)  d_in[1];
  const float* emb      = (const float*)d_in[2];
  const float* fc_z_w   = (const float*)d_in[3];
  const float* fc_z_b   = (const float*)d_in[4];
  const float* gru_wih  = (const float*)d_in[5];
  const float* gru_whh  = (const float*)d_in[6];
  const float* gru_bih  = (const float*)d_in[7];
  const float* gru_bhh  = (const float*)d_in[8];
  const float* lstm_wih = (const float*)d_in[9];
  const float* lstm_whh = (const float*)d_in[10];
  const float* lstm_bih = (const float*)d_in[11];
  const float* lstm_bhh = (const float*)d_in[12];
  const float* out_w    = (const float*)d_in[13];
  const float* out_b    = (const float*)d_in[14];
  char*  ws  = (char*)d_ws;
  float* out = (float*)d_out;

  const unsigned short* gruw  = (const unsigned short*)(ws + OFF_GRUW);
  const unsigned short* tblp  = (const unsigned short*)(ws + OFF_TBL);
  const unsigned short* lstmw = (const unsigned short*)(ws + OFF_LSTMW);
  const unsigned short* outw  = (const unsigned short*)(ws + OFF_OUTW);
  const unsigned short* fczw  = (const unsigned short*)(ws + OFF_FCZW);
  const float*          lbias = (const float*)(ws + OFF_LBIAS);
  unsigned short*       ybuf  = (unsigned short*)(ws + OFF_Y);

  // prep_main: 49152+114688+4096+8192+448 = 176576 -> 690 blocks
  prep_main_kernel<<<690, 256, 0, stream>>>(fc_z_w, gru_whh, lstm_wih, lstm_whh,
                                            lstm_bih, lstm_bhh, out_w, ws);
  prep_table_kernel<<<24, 512, 0, stream>>>(emb, gru_wih, gru_bih, ws);
  gru_kernel<<<512, 512, 0, stream>>>(z, x_in, fc_z_b, gru_bhh,
                                      gruw, tblp, fczw, ybuf);
  lstm_kernel<<<256, 512, 0, stream>>>(lstmw, lbias, ybuf, out_b, outw, out);
}